// Round 3
// baseline (600.232 us; speedup 1.0000x reference)
//
#include <hip/hip_runtime.h>
#include <cstdint>

#define Dd 2048
#define Tt 512
#define Bb 32
#define Kc 512
#define Nn 16384   // B*T

typedef _Float16 half8 __attribute__((ext_vector_type(8)));
typedef float f32x4 __attribute__((ext_vector_type(4)));

__device__ __forceinline__ float sqf(float v) { return v * v; }

__device__ __forceinline__ unsigned int fenc(float f) {
  unsigned int u = __float_as_uint(f);
  return (u & 0x80000000u) ? ~u : (u | 0x80000000u);
}

__device__ __forceinline__ unsigned long long ullmin(unsigned long long a,
                                                     unsigned long long b) {
  return b < a ? b : a;
}

// async global->LDS, 16B per lane (dest = wave-uniform base + lane*16)
__device__ __forceinline__ void gload_lds16(const _Float16* g, _Float16* l) {
  __builtin_amdgcn_global_load_lds(
      (const __attribute__((address_space(1))) void*)g,
      (__attribute__((address_space(3))) void*)l, 16, 0, 0);
}

// ================= MAIN PATH =================

// ---- k_splitz: LDS-tiled transpose. Reads z (B,D,T) t-coalesced,
//      writes zh/zl (N,D) d-coalesced. Bc partials via validated numpy tree.
__global__ __launch_bounds__(256) void k_splitz(const float* __restrict__ z,
                                                _Float16* __restrict__ zh,
                                                _Float16* __restrict__ zl,
                                                float* __restrict__ Bc) {
  __shared__ float sbuf[64 * 130];
  __shared__ float Ps[4 * 64];
  const int tid = threadIdx.x;
  const int t0  = blockIdx.x * 64;
  const int b   = blockIdx.y;
  const int cg  = blockIdx.z;        // 0..3 -> c = cg*4 + ci
  const int tt  = tid & 63;
  const int w   = tid >> 6;          // wave id 0..3

  for (int ci = 0; ci < 4; ++ci) {
    const int c = cg * 4 + ci;
    const float* zp = z + (size_t)b * Dd * Tt + (size_t)(c * 128) * Tt + t0;
    __syncthreads();
    #pragma unroll
    for (int i = 0; i < 32; ++i) {
      const int d = i * 4 + w;
      sbuf[tt * 130 + d] = zp[(size_t)d * Tt + tt];
    }
    __syncthreads();
    {
      const float* row = &sbuf[tt * 130];
      const int j = 2 * w;
      float r0 = sqf(row[j]);
      float r1 = sqf(row[j + 1]);
      #pragma unroll
      for (int s = 1; s < 16; ++s) {
        r0 += sqf(row[j + 8 * s]);
        r1 += sqf(row[j + 1 + 8 * s]);
      }
      Ps[w * 64 + tt] = r0 + r1;
    }
    {
      const int chunk = tid & 15;
      const int rr    = tid >> 4;
      #pragma unroll
      for (int p = 0; p < 4; ++p) {
        const int t = p * 16 + rr;
        const float* src = &sbuf[t * 130 + chunk * 8];
        __align__(16) _Float16 hbuf[8], lbuf[8];
        #pragma unroll
        for (int jj = 0; jj < 8; ++jj) {
          float v = src[jj];
          _Float16 h = (_Float16)v;
          hbuf[jj] = h;
          lbuf[jj] = (_Float16)((v - (float)h) * 4096.f);
        }
        const size_t off = (size_t)(b * Tt + t0 + t) * Dd + c * 128 + chunk * 8;
        *(float4*)(zh + off) = *(float4*)hbuf;
        *(float4*)(zl + off) = *(float4*)lbuf;
      }
    }
    __syncthreads();
    if (tid < 64) {
      const float B = (Ps[tid] + Ps[64 + tid]) + (Ps[128 + tid] + Ps[192 + tid]);
      Bc[c * Nn + b * Tt + t0 + tid] = B;
    }
  }
}

// ---- k_prep2: cnorm (numpy-pairwise), qd, + codebook f16 split planes
__global__ __launch_bounds__(256) void k_prep2(const float* __restrict__ cb,
                                               const float* __restrict__ w,
                                               float* __restrict__ cnorm,
                                               float* __restrict__ qd,
                                               _Float16* __restrict__ chp,
                                               _Float16* __restrict__ clp) {
  __shared__ float Bs[16 * 16];
  __shared__ float Qs[16 * 16];
  const int tid = threadIdx.x;
  const int kl  = tid >> 4;
  const int blk = tid & 15;
  const int k = blockIdx.x * 16 + kl;
  const float* row = cb + (size_t)k * Dd + blk * 128;
  const float* wp  = w + blk * 128;
  _Float16* ch_o = chp + (size_t)k * Dd + blk * 128;
  _Float16* cl_o = clp + (size_t)k * Dd + blk * 128;
  __align__(16) _Float16 hbuf[8], lbuf[8];
  float r[8];
  float q = 0.f;
  for (int s = 0; s < 16; ++s) {
    #pragma unroll
    for (int j = 0; j < 8; ++j) {
      int p = s * 8 + j;
      float v = row[p];
      float sq = v * v;
      if (s == 0) r[j] = sq; else r[j] += sq;
      q = fmaf(v, wp[p], q);
      _Float16 h = (_Float16)v;
      hbuf[j] = h;
      lbuf[j] = (_Float16)((v - (float)h) * 4096.f);
    }
    *(float4*)(ch_o + s * 8) = *(float4*)hbuf;
    *(float4*)(cl_o + s * 8) = *(float4*)lbuf;
  }
  float B = ((r[0] + r[1]) + (r[2] + r[3])) + ((r[4] + r[5]) + (r[6] + r[7]));
  Bs[kl * 16 + blk] = B;
  Qs[kl * 16 + blk] = q;
  __syncthreads();
  if (blk == 0) {
    const float* bb = &Bs[kl * 16];
    float d0 = (bb[0] + bb[1]) + (bb[2] + bb[3]);
    float d1 = (bb[4] + bb[5]) + (bb[6] + bb[7]);
    float d2 = (bb[8] + bb[9]) + (bb[10] + bb[11]);
    float d3 = (bb[12] + bb[13]) + (bb[14] + bb[15]);
    cnorm[k] = (d0 + d1) + (d2 + d3);
    const float* qq = &Qs[kl * 16];
    float s = 0.f;
    #pragma unroll
    for (int i = 0; i < 16; ++i) s += qq[i];
    qd[k] = s;
  }
}

// ---- k_prep_nb: norms-only variant for the small-ws fallback path
__global__ __launch_bounds__(256) void k_prep_nb(const float* __restrict__ cb,
                                                 const float* __restrict__ w,
                                                 float* __restrict__ cnorm,
                                                 float* __restrict__ qd) {
  __shared__ float Bs[16 * 16];
  __shared__ float Qs[16 * 16];
  const int tid = threadIdx.x;
  const int kl  = tid >> 4;
  const int blk = tid & 15;
  const int k = blockIdx.x * 16 + kl;
  const float* row = cb + (size_t)k * Dd + blk * 128;
  const float* wp  = w + blk * 128;
  float r[8];
  float q = 0.f;
  for (int s = 0; s < 16; ++s) {
    #pragma unroll
    for (int j = 0; j < 8; ++j) {
      int p = s * 8 + j;
      float v = row[p];
      float sq = v * v;
      if (s == 0) r[j] = sq; else r[j] += sq;
      q = fmaf(v, wp[p], q);
    }
  }
  float B = ((r[0] + r[1]) + (r[2] + r[3])) + ((r[4] + r[5]) + (r[6] + r[7]));
  Bs[kl * 16 + blk] = B;
  Qs[kl * 16 + blk] = q;
  __syncthreads();
  if (blk == 0) {
    const float* bb = &Bs[kl * 16];
    float d0 = (bb[0] + bb[1]) + (bb[2] + bb[3]);
    float d1 = (bb[4] + bb[5]) + (bb[6] + bb[7]);
    float d2 = (bb[8] + bb[9]) + (bb[10] + bb[11]);
    float d3 = (bb[12] + bb[13]) + (bb[14] + bb[15]);
    cnorm[k] = (d0 + d1) + (d2 + d3);
    const float* qq = &Qs[kl * 16];
    float s = 0.f;
    #pragma unroll
    for (int i = 0; i < 16; ++i) s += qq[i];
    qd[k] = s;
  }
}

// ---- k_gemm_mfma v2: m97-pattern (global_load_lds, linear LDS, 2 barriers),
//      split-f16 3-pass MFMA argmin-GEMM + fused xnorm combine.
__global__ __launch_bounds__(256, 3) void k_gemm_mfma(
    const _Float16* __restrict__ zh, const _Float16* __restrict__ zl,
    const _Float16* __restrict__ ch, const _Float16* __restrict__ cl,
    const float* __restrict__ Bc, const float* __restrict__ cnorm,
    unsigned long long* __restrict__ keys) {
  const int n0 = blockIdx.x * 128;
  const int k0 = blockIdx.y * 128;

  // linear tiles: Ah|Al|Bh|Bl, each [128 rows][32 f16] (64B rows) = 8KB, total 32KB
  __shared__ __align__(16) _Float16 smem[4 * 128 * 32];
  __shared__ unsigned long long keybuf[128][2];
  __shared__ float xn_s[128];

  const int tid = threadIdx.x;

  // fused k_xcomb: exact numpy tree over 16 Bc block sums (bit-identical)
  if (tid < 128) {
    const int n = n0 + tid;
    float bb[16];
    #pragma unroll
    for (int c = 0; c < 16; ++c) bb[c] = Bc[c * Nn + n];
    float d0 = (bb[0] + bb[1]) + (bb[2] + bb[3]);
    float d1 = (bb[4] + bb[5]) + (bb[6] + bb[7]);
    float d2 = (bb[8] + bb[9]) + (bb[10] + bb[11]);
    float d3 = (bb[12] + bb[13]) + (bb[14] + bb[15]);
    xn_s[tid] = (d0 + d1) + (d2 + d3);
  }

  const int lane = tid & 63;
  const int wid  = tid >> 6;
  const int wr   = wid >> 1, wc = wid & 1;
  const int lrow = lane & 15, lq = lane >> 4;

  f32x4 acc_h[4][4], acc_x[4][4];
  #pragma unroll
  for (int i = 0; i < 4; ++i)
    #pragma unroll
    for (int j = 0; j < 4; ++j) {
      acc_h[i][j] = (f32x4)0.f;
      acc_x[i][j] = (f32x4)0.f;
    }

  // staging map: lane covers (row = wave*16 + lane>>2, col = (lane&3)*8)
  const int srow = tid >> 2;
  const int scol = (tid & 3) * 8;
  const _Float16* gsrc0 = zh + (size_t)(n0 + srow) * Dd + scol;
  const _Float16* gsrc1 = zl + (size_t)(n0 + srow) * Dd + scol;
  const _Float16* gsrc2 = ch + (size_t)(k0 + srow) * Dd + scol;
  const _Float16* gsrc3 = cl + (size_t)(k0 + srow) * Dd + scol;
  _Float16* ldst = smem + tid * 8;   // + i*2048 per segment

  const _Float16* Ah = smem;
  const _Float16* Al = smem + 4096;
  const _Float16* Bh = smem + 8192;
  const _Float16* Bl = smem + 12288;
  const size_t half_skip = (size_t)64 * Dd;

  for (int dt = 0; dt < Dd / 32; ++dt) {
    const int doff = dt * 32;
    __syncthreads();   // previous tile fully consumed
    gload_lds16(gsrc0 + doff,             ldst);
    gload_lds16(gsrc0 + half_skip + doff, ldst + 2048);
    gload_lds16(gsrc1 + doff,             ldst + 4096);
    gload_lds16(gsrc1 + half_skip + doff, ldst + 6144);
    gload_lds16(gsrc2 + doff,             ldst + 8192);
    gload_lds16(gsrc2 + half_skip + doff, ldst + 10240);
    gload_lds16(gsrc3 + doff,             ldst + 12288);
    gload_lds16(gsrc3 + half_skip + doff, ldst + 14336);
    __syncthreads();   // vmcnt drained before barrier -> tile visible

    half8 ah[4], al[4];
    #pragma unroll
    for (int i = 0; i < 4; ++i) {
      int row = wr * 64 + i * 16 + lrow;
      ah[i] = *(const half8*)&Ah[row * 32 + lq * 8];
      al[i] = *(const half8*)&Al[row * 32 + lq * 8];
    }
    #pragma unroll
    for (int j = 0; j < 4; ++j) {
      int row = wc * 64 + j * 16 + lrow;
      half8 bh = *(const half8*)&Bh[row * 32 + lq * 8];
      half8 bl = *(const half8*)&Bl[row * 32 + lq * 8];
      #pragma unroll
      for (int i = 0; i < 4; ++i) {
        acc_h[i][j] = __builtin_amdgcn_mfma_f32_16x16x32_f16(ah[i], bh, acc_h[i][j], 0, 0, 0);
        acc_x[i][j] = __builtin_amdgcn_mfma_f32_16x16x32_f16(ah[i], bl, acc_x[i][j], 0, 0, 0);
        acc_x[i][j] = __builtin_amdgcn_mfma_f32_16x16x32_f16(al[i], bh, acc_x[i][j], 0, 0, 0);
      }
    }
  }

  // epilogue: dist = fl(fl(xnorm - 2*dot) + cnorm); keyed argmin, first-min ties
  float cn[4];
  #pragma unroll
  for (int j = 0; j < 4; ++j) cn[j] = cnorm[k0 + wc * 64 + j * 16 + lrow];

  #pragma unroll
  for (int i = 0; i < 4; ++i) {
    #pragma unroll
    for (int reg = 0; reg < 4; ++reg) {
      const int rowl = wr * 64 + i * 16 + lq * 4 + reg;
      const float xn = xn_s[rowl];
      unsigned long long best = ~0ull;
      #pragma unroll
      for (int j = 0; j < 4; ++j) {
        float dot = acc_h[i][j][reg] + acc_x[i][j][reg] * 0x1p-12f;
        float d = fmaf(-2.f, dot, xn) + cn[j];
        unsigned int code = (unsigned int)(k0 + wc * 64 + j * 16 + lrow);
        unsigned long long key = ((unsigned long long)fenc(d) << 32) | code;
        best = ullmin(best, key);
      }
      #pragma unroll
      for (int m = 1; m < 16; m <<= 1)
        best = ullmin(best, (unsigned long long)__shfl_xor((unsigned long long)best, m, 64));
      if (lrow == 0) keybuf[rowl][wc] = best;
    }
  }
  __syncthreads();
  if (tid < 128) {
    unsigned long long kk = ullmin(keybuf[tid][0], keybuf[tid][1]);
    atomicMin(&keys[n0 + tid], kk);
  }
}

// ---- k_scatter v2: decodes keys directly, writes quantized planes AND
//      the conv outputs (fused k_final; identical qd[k]+bc arithmetic).
__global__ __launch_bounds__(256) void k_scatter(const float* __restrict__ cb,
                                                 const unsigned long long* __restrict__ keys,
                                                 const float* __restrict__ qd,
                                                 const float* __restrict__ bconv,
                                                 float* __restrict__ out0,
                                                 float* __restrict__ out1,
                                                 float* __restrict__ out2,
                                                 float* __restrict__ out3) {
  const int d0 = blockIdx.x * 16;
  const int b  = blockIdx.y;
  __shared__ float cb_s[512 * 17];
  const int tid = threadIdx.x;
  {
    const int kk = tid >> 2;
    const int dq = tid & 3;
    #pragma unroll
    for (int p = 0; p < 8; ++p) {
      int k = p * 64 + kk;
      float4 v = *(const float4*)(cb + (size_t)k * Dd + d0 + dq * 4);
      cb_s[k * 17 + dq * 4 + 0] = v.x;
      cb_s[k * 17 + dq * 4 + 1] = v.y;
      cb_s[k * 17 + dq * 4 + 2] = v.z;
      cb_s[k * 17 + dq * 4 + 3] = v.w;
    }
  }
  const int t4 = (tid & 127) * 4;
  const unsigned long long* kp = keys + b * Tt + t4;
  int4 idx4;
  idx4.x = (int)(kp[0] & 0xFFFFFFFFull);
  idx4.y = (int)(kp[1] & 0xFFFFFFFFull);
  idx4.z = (int)(kp[2] & 0xFFFFFFFFull);
  idx4.w = (int)(kp[3] & 0xFFFFFFFFull);
  if (blockIdx.x == 0 && tid < 128) {
    const float bc0 = bconv[0];
    float4 o1;
    o1.x = qd[idx4.x] + bc0;
    o1.y = qd[idx4.y] + bc0;
    o1.z = qd[idx4.z] + bc0;
    o1.w = qd[idx4.w] + bc0;
    *(float4*)(out1 + b * Tt + t4) = o1;
    *(float4*)(out3 + b * Tt + t4) = o1;
  }
  __syncthreads();
  const int dhalf = tid >> 7;
  #pragma unroll
  for (int p = 0; p < 8; ++p) {
    int dd = p * 2 + dhalf;
    float4 o;
    o.x = cb_s[idx4.x * 17 + dd];
    o.y = cb_s[idx4.y * 17 + dd];
    o.z = cb_s[idx4.z * 17 + dd];
    o.w = cb_s[idx4.w * 17 + dd];
    size_t off = (size_t)b * Dd * Tt + (size_t)(d0 + dd) * Tt + t4;
    *(float4*)(out0 + off) = o;
    *(float4*)(out2 + off) = o;
  }
}

// ================= FALLBACK (round-2 validated fp32 path) =================

__global__ __launch_bounds__(256) void k_xnorm(const float* __restrict__ z,
                                               float* __restrict__ xnorm) {
  const int t0 = blockIdx.x * 64;
  const int b  = blockIdx.y;
  __shared__ float sbuf[128 * 64];
  __shared__ float Ps[256];
  __shared__ float Bs2[64 * 16];
  const int tid = threadIdx.x;
  const int tt = tid & 63;
  const int j2 = tid >> 6;
  const float* zb = z + (size_t)b * Dd * Tt + t0;
  for (int c = 0; c < 16; ++c) {
    __syncthreads();
    #pragma unroll
    for (int it = 0; it < 32; ++it) {
      int d = j2 + it * 4;
      sbuf[d * 64 + tt] = zb[(size_t)(c * 128 + d) * Tt + tt];
    }
    __syncthreads();
    float r0, r1;
    {
      const int j = 2 * j2;
      r0 = sqf(sbuf[j * 64 + tt]);
      #pragma unroll
      for (int s = 1; s < 16; ++s) r0 += sqf(sbuf[(j + 8 * s) * 64 + tt]);
      r1 = sqf(sbuf[(j + 1) * 64 + tt]);
      #pragma unroll
      for (int s = 1; s < 16; ++s) r1 += sqf(sbuf[(j + 1 + 8 * s) * 64 + tt]);
    }
    Ps[j2 * 64 + tt] = r0 + r1;
    __syncthreads();
    if (tid < 64) {
      float B = (Ps[tid] + Ps[64 + tid]) + (Ps[128 + tid] + Ps[192 + tid]);
      Bs2[tid * 16 + c] = B;
    }
  }
  __syncthreads();
  if (tid < 64) {
    const float* bb = &Bs2[tid * 16];
    float d0 = (bb[0] + bb[1]) + (bb[2] + bb[3]);
    float d1 = (bb[4] + bb[5]) + (bb[6] + bb[7]);
    float d2 = (bb[8] + bb[9]) + (bb[10] + bb[11]);
    float d3 = (bb[12] + bb[13]) + (bb[14] + bb[15]);
    xnorm[b * Tt + t0 + tid] = (d0 + d1) + (d2 + d3);
  }
}

__global__ __launch_bounds__(256, 2) void k_gemm(const float* __restrict__ z,
                                                 const float* __restrict__ cb,
                                                 const float* __restrict__ cnorm,
                                                 const float* __restrict__ xnorm,
                                                 unsigned long long* __restrict__ keys) {
  const int n0 = blockIdx.x * 128;
  const int k0 = blockIdx.y * 128;
  const int b  = n0 >> 9;
  const int t0 = n0 & 511;
  const float* zbase = z + (size_t)b * Dd * Tt + t0;

  __shared__ __align__(16) float As[32 * 132];
  __shared__ __align__(16) float Cs[32 * 132];
  __shared__ float red_v[16 * 128];
  __shared__ int   red_i[16 * 128];

  const int tid = threadIdx.x;
  const int t4a = (tid & 31) * 4;
  const int dla = tid >> 5;
  const int kc  = tid >> 3;
  const int dq  = tid & 7;
  const int r0  = (tid & 15) * 8;
  const int c0  = (tid >> 4) * 8;

  float4 pa[4], pc[4];
  {
    #pragma unroll
    for (int p = 0; p < 4; ++p)
      pa[p] = *(const float4*)(zbase + (size_t)(dla + p * 8) * Tt + t4a);
    const float* cp = cb + (size_t)(k0 + kc) * Dd + dq * 4;
    #pragma unroll
    for (int p = 0; p < 4; ++p)
      pc[p] = *(const float4*)(cp + (size_t)p * 32 * Dd);
  }

  float acc[8][8];
  #pragma unroll
  for (int i = 0; i < 8; ++i)
    #pragma unroll
    for (int j = 0; j < 8; ++j) acc[i][j] = 0.f;

  for (int dt = 0; dt < Dd / 32; ++dt) {
    __syncthreads();
    #pragma unroll
    for (int p = 0; p < 4; ++p)
      *(float4*)&As[(dla + p * 8) * 132 + t4a] = pa[p];
    #pragma unroll
    for (int p = 0; p < 4; ++p) {
      Cs[(dq * 4 + 0) * 132 + kc + p * 32] = pc[p].x;
      Cs[(dq * 4 + 1) * 132 + kc + p * 32] = pc[p].y;
      Cs[(dq * 4 + 2) * 132 + kc + p * 32] = pc[p].z;
      Cs[(dq * 4 + 3) * 132 + kc + p * 32] = pc[p].w;
    }
    __syncthreads();
    if (dt + 1 < Dd / 32) {
      const float* zp = zbase + (size_t)(dt + 1) * 32 * Tt;
      #pragma unroll
      for (int p = 0; p < 4; ++p)
        pa[p] = *(const float4*)(zp + (size_t)(dla + p * 8) * Tt + t4a);
      const float* cp = cb + (size_t)(k0 + kc) * Dd + (dt + 1) * 32 + dq * 4;
      #pragma unroll
      for (int p = 0; p < 4; ++p)
        pc[p] = *(const float4*)(cp + (size_t)p * 32 * Dd);
    }
    #pragma unroll 8
    for (int dl = 0; dl < 32; ++dl) {
      float4 a0 = *(const float4*)&As[dl * 132 + r0];
      float4 a1 = *(const float4*)&As[dl * 132 + r0 + 4];
      float4 b0 = *(const float4*)&Cs[dl * 132 + c0];
      float4 b1 = *(const float4*)&Cs[dl * 132 + c0 + 4];
      float av[8] = {a0.x, a0.y, a0.z, a0.w, a1.x, a1.y, a1.z, a1.w};
      float bv[8] = {b0.x, b0.y, b0.z, b0.w, b1.x, b1.y, b1.z, b1.w};
      #pragma unroll
      for (int i = 0; i < 8; ++i)
        #pragma unroll
        for (int j = 0; j < 8; ++j)
          acc[i][j] = fmaf(av[i], bv[j], acc[i][j]);
    }
  }

  float cn[8];
  #pragma unroll
  for (int j = 0; j < 8; ++j) cn[j] = cnorm[k0 + c0 + j];
  float xnv[8];
  #pragma unroll
  for (int i = 0; i < 8; ++i) xnv[i] = xnorm[n0 + r0 + i];

  const int c16 = tid >> 4;
  #pragma unroll
  for (int i = 0; i < 8; ++i) {
    float bv = fmaf(-2.f, acc[i][0], xnv[i]) + cn[0];
    int bi = 0;
    #pragma unroll
    for (int j = 1; j < 8; ++j) {
      float d = fmaf(-2.f, acc[i][j], xnv[i]) + cn[j];
      if (d < bv) { bv = d; bi = j; }
    }
    red_v[c16 * 128 + r0 + i] = bv;
    red_i[c16 * 128 + r0 + i] = k0 + c0 + bi;
  }
  __syncthreads();
  if (tid < 128) {
    float bv = red_v[tid];
    int bi = red_i[tid];
    #pragma unroll
    for (int j = 1; j < 16; ++j) {
      float v = red_v[j * 128 + tid];
      if (v < bv) { bv = v; bi = red_i[j * 128 + tid]; }
    }
    unsigned long long key = ((unsigned long long)fenc(bv) << 32) | (unsigned int)bi;
    atomicMin(&keys[n0 + tid], key);
  }
}

// ================= launch =================

extern "C" void kernel_launch(void* const* d_in, const int* in_sizes, int n_in,
                              void* d_out, int out_size, void* d_ws, size_t ws_size,
                              hipStream_t stream) {
  const float* z  = (const float*)d_in[0];   // (B, D, T)
  const float* cb = (const float*)d_in[1];   // (K, D)
  const float* w  = (const float*)d_in[2];   // (D,)
  const float* bc = (const float*)d_in[3];   // (1,)

  float* out0 = (float*)d_out;               // (B, D, T)
  float* out1 = out0 + (size_t)Bb * Dd * Tt; // (B, 1, T)
  float* out2 = out1 + (size_t)Bb * Tt;      // (B, D, T)
  float* out3 = out2 + (size_t)Bb * Dd * Tt; // (B, 1, T)

  char* ws = (char*)d_ws;
  unsigned long long* keys = (unsigned long long*)ws;         // 131072
  float* cnorm = (float*)(ws + 131072);                       // 2048
  float* qd    = (float*)(ws + 133120);                       // 2048
  float* xnorm = (float*)(ws + 200704);                       // 65536 (fallback)
  float* Bc    = (float*)(ws + 266240);                       // 1 MB
  _Float16* chp = (_Float16*)(ws + 1314816);                  // 2 MB
  _Float16* clp = (_Float16*)(ws + 3411968);                  // 2 MB
  _Float16* zh  = (_Float16*)(ws + 5509120);                  // 64 MB
  _Float16* zl  = (_Float16*)(ws + 72617984);                 // 64 MB
  const size_t need = 139726848;

  hipMemsetAsync(keys, 0xFF, (size_t)Nn * 8, stream);

  if (ws_size >= need) {
    k_splitz<<<dim3(Tt / 64, Bb, 4), dim3(256), 0, stream>>>(z, zh, zl, Bc);
    k_prep2<<<dim3(Kc / 16), dim3(256), 0, stream>>>(cb, w, cnorm, qd, chp, clp);
    k_gemm_mfma<<<dim3(Nn / 128, Kc / 128), dim3(256), 0, stream>>>(
        zh, zl, chp, clp, Bc, cnorm, keys);
  } else {
    k_xnorm<<<dim3(Tt / 64, Bb), dim3(256), 0, stream>>>(z, xnorm);
    k_prep_nb<<<dim3(Kc / 16), dim3(256), 0, stream>>>(cb, w, cnorm, qd);
    k_gemm<<<dim3(Nn / 128, Kc / 128), dim3(256), 0, stream>>>(z, cb, cnorm, xnorm, keys);
  }
  k_scatter<<<dim3(Dd / 16, Bb), dim3(256), 0, stream>>>(cb, keys, qd, bc,
                                                         out0, out1, out2, out3);
}

// Round 4
// 530.788 us; speedup vs baseline: 1.1308x; 1.1308x over previous
//
#include <hip/hip_runtime.h>
#include <cstdint>

#define Dd 2048
#define Tt 512
#define Bb 32
#define Kc 512
#define Nn 16384   // B*T

typedef _Float16 half8 __attribute__((ext_vector_type(8)));
typedef float f32x4 __attribute__((ext_vector_type(4)));

__device__ __forceinline__ float sqf(float v) { return v * v; }

__device__ __forceinline__ unsigned int fenc(float f) {
  unsigned int u = __float_as_uint(f);
  return (u & 0x80000000u) ? ~u : (u | 0x80000000u);
}

__device__ __forceinline__ unsigned long long ullmin(unsigned long long a,
                                                     unsigned long long b) {
  return b < a ? b : a;
}

// async global->LDS, 16B per lane (dest = wave-uniform base + lane*16)
__device__ __forceinline__ void gload_lds16(const _Float16* g, _Float16* l) {
  __builtin_amdgcn_global_load_lds(
      (const __attribute__((address_space(1))) void*)g,
      (__attribute__((address_space(3))) void*)l, 16, 0, 0);
}

// ================= MAIN PATH =================

// ---- k_splitz: LDS-tiled transpose. Reads z (B,D,T) t-coalesced,
//      writes zh/zl (N,D) d-coalesced. Bc partials via validated numpy tree.
__global__ __launch_bounds__(256) void k_splitz(const float* __restrict__ z,
                                                _Float16* __restrict__ zh,
                                                _Float16* __restrict__ zl,
                                                float* __restrict__ Bc) {
  __shared__ float sbuf[64 * 130];
  __shared__ float Ps[4 * 64];
  const int tid = threadIdx.x;
  const int t0  = blockIdx.x * 64;
  const int b   = blockIdx.y;
  const int cg  = blockIdx.z;        // 0..3 -> c = cg*4 + ci
  const int tt  = tid & 63;
  const int w   = tid >> 6;          // wave id 0..3

  for (int ci = 0; ci < 4; ++ci) {
    const int c = cg * 4 + ci;
    const float* zp = z + (size_t)b * Dd * Tt + (size_t)(c * 128) * Tt + t0;
    __syncthreads();
    #pragma unroll
    for (int i = 0; i < 32; ++i) {
      const int d = i * 4 + w;
      sbuf[tt * 130 + d] = zp[(size_t)d * Tt + tt];
    }
    __syncthreads();
    {
      const float* row = &sbuf[tt * 130];
      const int j = 2 * w;
      float r0 = sqf(row[j]);
      float r1 = sqf(row[j + 1]);
      #pragma unroll
      for (int s = 1; s < 16; ++s) {
        r0 += sqf(row[j + 8 * s]);
        r1 += sqf(row[j + 1 + 8 * s]);
      }
      Ps[w * 64 + tt] = r0 + r1;
    }
    {
      const int chunk = tid & 15;
      const int rr    = tid >> 4;
      #pragma unroll
      for (int p = 0; p < 4; ++p) {
        const int t = p * 16 + rr;
        const float* src = &sbuf[t * 130 + chunk * 8];
        __align__(16) _Float16 hbuf[8], lbuf[8];
        #pragma unroll
        for (int jj = 0; jj < 8; ++jj) {
          float v = src[jj];
          _Float16 h = (_Float16)v;
          hbuf[jj] = h;
          lbuf[jj] = (_Float16)((v - (float)h) * 4096.f);
        }
        const size_t off = (size_t)(b * Tt + t0 + t) * Dd + c * 128 + chunk * 8;
        *(float4*)(zh + off) = *(float4*)hbuf;
        *(float4*)(zl + off) = *(float4*)lbuf;
      }
    }
    __syncthreads();
    if (tid < 64) {
      const float B = (Ps[tid] + Ps[64 + tid]) + (Ps[128 + tid] + Ps[192 + tid]);
      Bc[c * Nn + b * Tt + t0 + tid] = B;
    }
  }
}

// ---- k_prep2: cnorm (numpy-pairwise), qd, + codebook f16 split planes
__global__ __launch_bounds__(256) void k_prep2(const float* __restrict__ cb,
                                               const float* __restrict__ w,
                                               float* __restrict__ cnorm,
                                               float* __restrict__ qd,
                                               _Float16* __restrict__ chp,
                                               _Float16* __restrict__ clp) {
  __shared__ float Bs[16 * 16];
  __shared__ float Qs[16 * 16];
  const int tid = threadIdx.x;
  const int kl  = tid >> 4;
  const int blk = tid & 15;
  const int k = blockIdx.x * 16 + kl;
  const float* row = cb + (size_t)k * Dd + blk * 128;
  const float* wp  = w + blk * 128;
  _Float16* ch_o = chp + (size_t)k * Dd + blk * 128;
  _Float16* cl_o = clp + (size_t)k * Dd + blk * 128;
  __align__(16) _Float16 hbuf[8], lbuf[8];
  float r[8];
  float q = 0.f;
  for (int s = 0; s < 16; ++s) {
    #pragma unroll
    for (int j = 0; j < 8; ++j) {
      int p = s * 8 + j;
      float v = row[p];
      float sq = v * v;
      if (s == 0) r[j] = sq; else r[j] += sq;
      q = fmaf(v, wp[p], q);
      _Float16 h = (_Float16)v;
      hbuf[j] = h;
      lbuf[j] = (_Float16)((v - (float)h) * 4096.f);
    }
    *(float4*)(ch_o + s * 8) = *(float4*)hbuf;
    *(float4*)(cl_o + s * 8) = *(float4*)lbuf;
  }
  float B = ((r[0] + r[1]) + (r[2] + r[3])) + ((r[4] + r[5]) + (r[6] + r[7]));
  Bs[kl * 16 + blk] = B;
  Qs[kl * 16 + blk] = q;
  __syncthreads();
  if (blk == 0) {
    const float* bb = &Bs[kl * 16];
    float d0 = (bb[0] + bb[1]) + (bb[2] + bb[3]);
    float d1 = (bb[4] + bb[5]) + (bb[6] + bb[7]);
    float d2 = (bb[8] + bb[9]) + (bb[10] + bb[11]);
    float d3 = (bb[12] + bb[13]) + (bb[14] + bb[15]);
    cnorm[k] = (d0 + d1) + (d2 + d3);
    const float* qq = &Qs[kl * 16];
    float s = 0.f;
    #pragma unroll
    for (int i = 0; i < 16; ++i) s += qq[i];
    qd[k] = s;
  }
}

// ---- k_prep_nb: norms-only variant for the small-ws fallback path
__global__ __launch_bounds__(256) void k_prep_nb(const float* __restrict__ cb,
                                                 const float* __restrict__ w,
                                                 float* __restrict__ cnorm,
                                                 float* __restrict__ qd) {
  __shared__ float Bs[16 * 16];
  __shared__ float Qs[16 * 16];
  const int tid = threadIdx.x;
  const int kl  = tid >> 4;
  const int blk = tid & 15;
  const int k = blockIdx.x * 16 + kl;
  const float* row = cb + (size_t)k * Dd + blk * 128;
  const float* wp  = w + blk * 128;
  float r[8];
  float q = 0.f;
  for (int s = 0; s < 16; ++s) {
    #pragma unroll
    for (int j = 0; j < 8; ++j) {
      int p = s * 8 + j;
      float v = row[p];
      float sq = v * v;
      if (s == 0) r[j] = sq; else r[j] += sq;
      q = fmaf(v, wp[p], q);
    }
  }
  float B = ((r[0] + r[1]) + (r[2] + r[3])) + ((r[4] + r[5]) + (r[6] + r[7]));
  Bs[kl * 16 + blk] = B;
  Qs[kl * 16 + blk] = q;
  __syncthreads();
  if (blk == 0) {
    const float* bb = &Bs[kl * 16];
    float d0 = (bb[0] + bb[1]) + (bb[2] + bb[3]);
    float d1 = (bb[4] + bb[5]) + (bb[6] + bb[7]);
    float d2 = (bb[8] + bb[9]) + (bb[10] + bb[11]);
    float d3 = (bb[12] + bb[13]) + (bb[14] + bb[15]);
    cnorm[k] = (d0 + d1) + (d2 + d3);
    const float* qq = &Qs[kl * 16];
    float s = 0.f;
    #pragma unroll
    for (int i = 0; i < 16; ++i) s += qq[i];
    qd[k] = s;
  }
}

// ---- k_gemm_mfma v3: double-buffered gload_lds pipeline with counted vmcnt
//      (T3/T4) + XOR bank swizzle via pre-swizzled global source (T2, m173).
//      Fragment values and MFMA order bit-identical to v2.
#define GSTAGE(dtv, bufp) do {                                       \
    const int doff_ = (dtv) * 32;                                    \
    gload_lds16(gsrc0 + doff_,             (bufp) + st_off);         \
    gload_lds16(gsrc0 + half_skip + doff_, (bufp) + st_off + 2048);  \
    gload_lds16(gsrc1 + doff_,             (bufp) + 4096 + st_off);  \
    gload_lds16(gsrc1 + half_skip + doff_, (bufp) + 4096 + st_off + 2048); \
    gload_lds16(gsrc2 + doff_,             (bufp) + 8192 + st_off);  \
    gload_lds16(gsrc2 + half_skip + doff_, (bufp) + 8192 + st_off + 2048); \
    gload_lds16(gsrc3 + doff_,             (bufp) + 12288 + st_off); \
    gload_lds16(gsrc3 + half_skip + doff_, (bufp) + 12288 + st_off + 2048); \
  } while (0)

#define GCOMPUTE(bufp) do {                                          \
    half8 ah_[4], al_[4];                                            \
    _Pragma("unroll")                                                \
    for (int i = 0; i < 4; ++i) {                                    \
      const int row_ = wr * 64 + i * 16 + lrow;                      \
      ah_[i] = *(const half8*)&(bufp)[row_ * 32 + cq];               \
      al_[i] = *(const half8*)&(bufp)[4096 + row_ * 32 + cq];        \
    }                                                                \
    _Pragma("unroll")                                                \
    for (int j = 0; j < 4; ++j) {                                    \
      const int rowb_ = wc * 64 + j * 16 + lrow;                     \
      half8 bh_ = *(const half8*)&(bufp)[8192 + rowb_ * 32 + cq];    \
      half8 bl_ = *(const half8*)&(bufp)[12288 + rowb_ * 32 + cq];   \
      _Pragma("unroll")                                              \
      for (int i = 0; i < 4; ++i) {                                  \
        acc_h[i][j] = __builtin_amdgcn_mfma_f32_16x16x32_f16(ah_[i], bh_, acc_h[i][j], 0, 0, 0); \
        acc_x[i][j] = __builtin_amdgcn_mfma_f32_16x16x32_f16(ah_[i], bl_, acc_x[i][j], 0, 0, 0); \
        acc_x[i][j] = __builtin_amdgcn_mfma_f32_16x16x32_f16(al_[i], bh_, acc_x[i][j], 0, 0, 0); \
      }                                                              \
    }                                                                \
  } while (0)

__global__ __launch_bounds__(256, 2) void k_gemm_mfma(
    const _Float16* __restrict__ zh, const _Float16* __restrict__ zl,
    const _Float16* __restrict__ ch, const _Float16* __restrict__ cl,
    const float* __restrict__ Bc, const float* __restrict__ cnorm,
    unsigned long long* __restrict__ keys) {
  const int n0 = blockIdx.x * 128;
  const int k0 = blockIdx.y * 128;

  // double-buffered linear tiles: {Ah|Al|Bh|Bl} x [128 rows][32 f16] = 32KB each
  __shared__ __align__(16) _Float16 smem[2 * 4 * 128 * 32];   // 64 KB
  __shared__ unsigned long long keybuf[128][2];
  __shared__ float xn_s[128];
  _Float16* buf0 = smem;
  _Float16* buf1 = smem + 16384;

  const int tid = threadIdx.x;

  // fused k_xcomb: exact numpy tree over 16 Bc block sums (bit-identical)
  if (tid < 128) {
    const int n = n0 + tid;
    float bb[16];
    #pragma unroll
    for (int c = 0; c < 16; ++c) bb[c] = Bc[c * Nn + n];
    float d0 = (bb[0] + bb[1]) + (bb[2] + bb[3]);
    float d1 = (bb[4] + bb[5]) + (bb[6] + bb[7]);
    float d2 = (bb[8] + bb[9]) + (bb[10] + bb[11]);
    float d3 = (bb[12] + bb[13]) + (bb[14] + bb[15]);
    xn_s[tid] = (d0 + d1) + (d2 + d3);
  }

  const int lane = tid & 63;
  const int wid  = tid >> 6;
  const int wr   = wid >> 1, wc = wid & 1;
  const int lrow = lane & 15, lq = lane >> 4;
  // swizzle: physical col-block = lq ^ ((row>>1)&3); for fragment rows,
  // (row>>1)&3 == (lrow>>1)&3 (lane-constant)
  const int cq = (lq ^ ((lrow >> 1) & 3)) * 8;

  f32x4 acc_h[4][4], acc_x[4][4];
  #pragma unroll
  for (int i = 0; i < 4; ++i)
    #pragma unroll
    for (int j = 0; j < 4; ++j) {
      acc_h[i][j] = (f32x4)0.f;
      acc_x[i][j] = (f32x4)0.f;
    }

  // staging map: thread covers LDS rows (tid>>2, +64), phys col-block tid&3.
  // Global source column is the INVERSE swizzle so linear LDS dest + swizzled
  // read reconstruct logical data (involution: same XOR).
  const int srow = tid >> 2;
  const int ssw  = (srow >> 1) & 3;
  const int scol = ((tid & 3) ^ ssw) * 8;
  const int st_off = tid * 8;   // f16 elements (16 B per thread)
  const _Float16* gsrc0 = zh + (size_t)(n0 + srow) * Dd + scol;
  const _Float16* gsrc1 = zl + (size_t)(n0 + srow) * Dd + scol;
  const _Float16* gsrc2 = ch + (size_t)(k0 + srow) * Dd + scol;
  const _Float16* gsrc3 = cl + (size_t)(k0 + srow) * Dd + scol;
  const size_t half_skip = (size_t)64 * Dd;

  // ---- software-pipelined K loop: 64 tiles, 2 per iteration
  GSTAGE(0, buf0);
  #pragma unroll 1
  for (int dt = 0; dt < 64; dt += 2) {
    GSTAGE(dt + 1, buf1);
    asm volatile("s_waitcnt vmcnt(8)" ::: "memory");
    __builtin_amdgcn_s_barrier();
    GCOMPUTE(buf0);
    asm volatile("s_waitcnt lgkmcnt(0)" ::: "memory");
    __builtin_amdgcn_s_barrier();

    if (dt + 2 < 64) {
      GSTAGE(dt + 2, buf0);
      asm volatile("s_waitcnt vmcnt(8)" ::: "memory");
    } else {
      asm volatile("s_waitcnt vmcnt(0)" ::: "memory");
    }
    __builtin_amdgcn_s_barrier();
    GCOMPUTE(buf1);
    asm volatile("s_waitcnt lgkmcnt(0)" ::: "memory");
    __builtin_amdgcn_s_barrier();
  }

  // epilogue: dist = fl(fl(xnorm - 2*dot) + cnorm); keyed argmin, first-min ties
  float cn[4];
  #pragma unroll
  for (int j = 0; j < 4; ++j) cn[j] = cnorm[k0 + wc * 64 + j * 16 + lrow];

  #pragma unroll
  for (int i = 0; i < 4; ++i) {
    #pragma unroll
    for (int reg = 0; reg < 4; ++reg) {
      const int rowl = wr * 64 + i * 16 + lq * 4 + reg;
      const float xn = xn_s[rowl];
      unsigned long long best = ~0ull;
      #pragma unroll
      for (int j = 0; j < 4; ++j) {
        float dot = acc_h[i][j][reg] + acc_x[i][j][reg] * 0x1p-12f;
        float d = fmaf(-2.f, dot, xn) + cn[j];
        unsigned int code = (unsigned int)(k0 + wc * 64 + j * 16 + lrow);
        unsigned long long key = ((unsigned long long)fenc(d) << 32) | code;
        best = ullmin(best, key);
      }
      #pragma unroll
      for (int m = 1; m < 16; m <<= 1)
        best = ullmin(best, (unsigned long long)__shfl_xor((unsigned long long)best, m, 64));
      if (lrow == 0) keybuf[rowl][wc] = best;
    }
  }
  __syncthreads();
  if (tid < 128) {
    unsigned long long kk = ullmin(keybuf[tid][0], keybuf[tid][1]);
    atomicMin(&keys[n0 + tid], kk);
  }
}

// ---- k_scatter v2: decodes keys directly, writes quantized planes AND
//      the conv outputs (fused k_final; identical qd[k]+bc arithmetic).
__global__ __launch_bounds__(256) void k_scatter(const float* __restrict__ cb,
                                                 const unsigned long long* __restrict__ keys,
                                                 const float* __restrict__ qd,
                                                 const float* __restrict__ bconv,
                                                 float* __restrict__ out0,
                                                 float* __restrict__ out1,
                                                 float* __restrict__ out2,
                                                 float* __restrict__ out3) {
  const int d0 = blockIdx.x * 16;
  const int b  = blockIdx.y;
  __shared__ float cb_s[512 * 17];
  const int tid = threadIdx.x;
  {
    const int kk = tid >> 2;
    const int dq = tid & 3;
    #pragma unroll
    for (int p = 0; p < 8; ++p) {
      int k = p * 64 + kk;
      float4 v = *(const float4*)(cb + (size_t)k * Dd + d0 + dq * 4);
      cb_s[k * 17 + dq * 4 + 0] = v.x;
      cb_s[k * 17 + dq * 4 + 1] = v.y;
      cb_s[k * 17 + dq * 4 + 2] = v.z;
      cb_s[k * 17 + dq * 4 + 3] = v.w;
    }
  }
  const int t4 = (tid & 127) * 4;
  const unsigned long long* kp = keys + b * Tt + t4;
  int4 idx4;
  idx4.x = (int)(kp[0] & 0xFFFFFFFFull);
  idx4.y = (int)(kp[1] & 0xFFFFFFFFull);
  idx4.z = (int)(kp[2] & 0xFFFFFFFFull);
  idx4.w = (int)(kp[3] & 0xFFFFFFFFull);
  if (blockIdx.x == 0 && tid < 128) {
    const float bc0 = bconv[0];
    float4 o1;
    o1.x = qd[idx4.x] + bc0;
    o1.y = qd[idx4.y] + bc0;
    o1.z = qd[idx4.z] + bc0;
    o1.w = qd[idx4.w] + bc0;
    *(float4*)(out1 + b * Tt + t4) = o1;
    *(float4*)(out3 + b * Tt + t4) = o1;
  }
  __syncthreads();
  const int dhalf = tid >> 7;
  #pragma unroll
  for (int p = 0; p < 8; ++p) {
    int dd = p * 2 + dhalf;
    float4 o;
    o.x = cb_s[idx4.x * 17 + dd];
    o.y = cb_s[idx4.y * 17 + dd];
    o.z = cb_s[idx4.z * 17 + dd];
    o.w = cb_s[idx4.w * 17 + dd];
    size_t off = (size_t)b * Dd * Tt + (size_t)(d0 + dd) * Tt + t4;
    *(float4*)(out0 + off) = o;
    *(float4*)(out2 + off) = o;
  }
}

// ================= FALLBACK (round-2 validated fp32 path) =================

__global__ __launch_bounds__(256) void k_xnorm(const float* __restrict__ z,
                                               float* __restrict__ xnorm) {
  const int t0 = blockIdx.x * 64;
  const int b  = blockIdx.y;
  __shared__ float sbuf[128 * 64];
  __shared__ float Ps[256];
  __shared__ float Bs2[64 * 16];
  const int tid = threadIdx.x;
  const int tt = tid & 63;
  const int j2 = tid >> 6;
  const float* zb = z + (size_t)b * Dd * Tt + t0;
  for (int c = 0; c < 16; ++c) {
    __syncthreads();
    #pragma unroll
    for (int it = 0; it < 32; ++it) {
      int d = j2 + it * 4;
      sbuf[d * 64 + tt] = zb[(size_t)(c * 128 + d) * Tt + tt];
    }
    __syncthreads();
    float r0, r1;
    {
      const int j = 2 * j2;
      r0 = sqf(sbuf[j * 64 + tt]);
      #pragma unroll
      for (int s = 1; s < 16; ++s) r0 += sqf(sbuf[(j + 8 * s) * 64 + tt]);
      r1 = sqf(sbuf[(j + 1) * 64 + tt]);
      #pragma unroll
      for (int s = 1; s < 16; ++s) r1 += sqf(sbuf[(j + 1 + 8 * s) * 64 + tt]);
    }
    Ps[j2 * 64 + tt] = r0 + r1;
    __syncthreads();
    if (tid < 64) {
      float B = (Ps[tid] + Ps[64 + tid]) + (Ps[128 + tid] + Ps[192 + tid]);
      Bs2[tid * 16 + c] = B;
    }
  }
  __syncthreads();
  if (tid < 64) {
    const float* bb = &Bs2[tid * 16];
    float d0 = (bb[0] + bb[1]) + (bb[2] + bb[3]);
    float d1 = (bb[4] + bb[5]) + (bb[6] + bb[7]);
    float d2 = (bb[8] + bb[9]) + (bb[10] + bb[11]);
    float d3 = (bb[12] + bb[13]) + (bb[14] + bb[15]);
    xnorm[b * Tt + t0 + tid] = (d0 + d1) + (d2 + d3);
  }
}

__global__ __launch_bounds__(256, 2) void k_gemm(const float* __restrict__ z,
                                                 const float* __restrict__ cb,
                                                 const float* __restrict__ cnorm,
                                                 const float* __restrict__ xnorm,
                                                 unsigned long long* __restrict__ keys) {
  const int n0 = blockIdx.x * 128;
  const int k0 = blockIdx.y * 128;
  const int b  = n0 >> 9;
  const int t0 = n0 & 511;
  const float* zbase = z + (size_t)b * Dd * Tt + t0;

  __shared__ __align__(16) float As[32 * 132];
  __shared__ __align__(16) float Cs[32 * 132];
  __shared__ float red_v[16 * 128];
  __shared__ int   red_i[16 * 128];

  const int tid = threadIdx.x;
  const int t4a = (tid & 31) * 4;
  const int dla = tid >> 5;
  const int kc  = tid >> 3;
  const int dq  = tid & 7;
  const int r0  = (tid & 15) * 8;
  const int c0  = (tid >> 4) * 8;

  float4 pa[4], pc[4];
  {
    #pragma unroll
    for (int p = 0; p < 4; ++p)
      pa[p] = *(const float4*)(zbase + (size_t)(dla + p * 8) * Tt + t4a);
    const float* cp = cb + (size_t)(k0 + kc) * Dd + dq * 4;
    #pragma unroll
    for (int p = 0; p < 4; ++p)
      pc[p] = *(const float4*)(cp + (size_t)p * 32 * Dd);
  }

  float acc[8][8];
  #pragma unroll
  for (int i = 0; i < 8; ++i)
    #pragma unroll
    for (int j = 0; j < 8; ++j) acc[i][j] = 0.f;

  for (int dt = 0; dt < Dd / 32; ++dt) {
    __syncthreads();
    #pragma unroll
    for (int p = 0; p < 4; ++p)
      *(float4*)&As[(dla + p * 8) * 132 + t4a] = pa[p];
    #pragma unroll
    for (int p = 0; p < 4; ++p) {
      Cs[(dq * 4 + 0) * 132 + kc + p * 32] = pc[p].x;
      Cs[(dq * 4 + 1) * 132 + kc + p * 32] = pc[p].y;
      Cs[(dq * 4 + 2) * 132 + kc + p * 32] = pc[p].z;
      Cs[(dq * 4 + 3) * 132 + kc + p * 32] = pc[p].w;
    }
    __syncthreads();
    if (dt + 1 < Dd / 32) {
      const float* zp = zbase + (size_t)(dt + 1) * 32 * Tt;
      #pragma unroll
      for (int p = 0; p < 4; ++p)
        pa[p] = *(const float4*)(zp + (size_t)(dla + p * 8) * Tt + t4a);
      const float* cp = cb + (size_t)(k0 + kc) * Dd + (dt + 1) * 32 + dq * 4;
      #pragma unroll
      for (int p = 0; p < 4; ++p)
        pc[p] = *(const float4*)(cp + (size_t)p * 32 * Dd);
    }
    #pragma unroll 8
    for (int dl = 0; dl < 32; ++dl) {
      float4 a0 = *(const float4*)&As[dl * 132 + r0];
      float4 a1 = *(const float4*)&As[dl * 132 + r0 + 4];
      float4 b0 = *(const float4*)&Cs[dl * 132 + c0];
      float4 b1 = *(const float4*)&Cs[dl * 132 + c0 + 4];
      float av[8] = {a0.x, a0.y, a0.z, a0.w, a1.x, a1.y, a1.z, a1.w};
      float bv[8] = {b0.x, b0.y, b0.z, b0.w, b1.x, b1.y, b1.z, b1.w};
      #pragma unroll
      for (int i = 0; i < 8; ++i)
        #pragma unroll
        for (int j = 0; j < 8; ++j)
          acc[i][j] = fmaf(av[i], bv[j], acc[i][j]);
    }
  }

  float cn[8];
  #pragma unroll
  for (int j = 0; j < 8; ++j) cn[j] = cnorm[k0 + c0 + j];
  float xnv[8];
  #pragma unroll
  for (int i = 0; i < 8; ++i) xnv[i] = xnorm[n0 + r0 + i];

  const int c16 = tid >> 4;
  #pragma unroll
  for (int i = 0; i < 8; ++i) {
    float bv = fmaf(-2.f, acc[i][0], xnv[i]) + cn[0];
    int bi = 0;
    #pragma unroll
    for (int j = 1; j < 8; ++j) {
      float d = fmaf(-2.f, acc[i][j], xnv[i]) + cn[j];
      if (d < bv) { bv = d; bi = j; }
    }
    red_v[c16 * 128 + r0 + i] = bv;
    red_i[c16 * 128 + r0 + i] = k0 + c0 + bi;
  }
  __syncthreads();
  if (tid < 128) {
    float bv = red_v[tid];
    int bi = red_i[tid];
    #pragma unroll
    for (int j = 1; j < 16; ++j) {
      float v = red_v[j * 128 + tid];
      if (v < bv) { bv = v; bi = red_i[j * 128 + tid]; }
    }
    unsigned long long key = ((unsigned long long)fenc(bv) << 32) | (unsigned int)bi;
    atomicMin(&keys[n0 + tid], key);
  }
}

// ================= launch =================

extern "C" void kernel_launch(void* const* d_in, const int* in_sizes, int n_in,
                              void* d_out, int out_size, void* d_ws, size_t ws_size,
                              hipStream_t stream) {
  const float* z  = (const float*)d_in[0];   // (B, D, T)
  const float* cb = (const float*)d_in[1];   // (K, D)
  const float* w  = (const float*)d_in[2];   // (D,)
  const float* bc = (const float*)d_in[3];   // (1,)

  float* out0 = (float*)d_out;               // (B, D, T)
  float* out1 = out0 + (size_t)Bb * Dd * Tt; // (B, 1, T)
  float* out2 = out1 + (size_t)Bb * Tt;      // (B, D, T)
  float* out3 = out2 + (size_t)Bb * Dd * Tt; // (B, 1, T)

  char* ws = (char*)d_ws;
  unsigned long long* keys = (unsigned long long*)ws;         // 131072
  float* cnorm = (float*)(ws + 131072);                       // 2048
  float* qd    = (float*)(ws + 133120);                       // 2048
  float* xnorm = (float*)(ws + 200704);                       // 65536 (fallback)
  float* Bc    = (float*)(ws + 266240);                       // 1 MB
  _Float16* chp = (_Float16*)(ws + 1314816);                  // 2 MB
  _Float16* clp = (_Float16*)(ws + 3411968);                  // 2 MB
  _Float16* zh  = (_Float16*)(ws + 5509120);                  // 64 MB
  _Float16* zl  = (_Float16*)(ws + 72617984);                 // 64 MB
  const size_t need = 139726848;

  hipMemsetAsync(keys, 0xFF, (size_t)Nn * 8, stream);

  if (ws_size >= need) {
    k_splitz<<<dim3(Tt / 64, Bb, 4), dim3(256), 0, stream>>>(z, zh, zl, Bc);
    k_prep2<<<dim3(Kc / 16), dim3(256), 0, stream>>>(cb, w, cnorm, qd, chp, clp);
    k_gemm_mfma<<<dim3(Nn / 128, Kc / 128), dim3(256), 0, stream>>>(
        zh, zl, chp, clp, Bc, cnorm, keys);
  } else {
    k_xnorm<<<dim3(Tt / 64, Bb), dim3(256), 0, stream>>>(z, xnorm);
    k_prep_nb<<<dim3(Kc / 16), dim3(256), 0, stream>>>(cb, w, cnorm, qd);
    k_gemm<<<dim3(Nn / 128, Kc / 128), dim3(256), 0, stream>>>(z, cb, cnorm, xnorm, keys);
  }
  k_scatter<<<dim3(Dd / 16, Bb), dim3(256), 0, stream>>>(cb, keys, qd, bc,
                                                         out0, out1, out2, out3);
}